// Round 7
// baseline (1325.232 us; speedup 1.0000x reference)
//
#include <hip/hip_runtime.h>
#include <hip/hip_bf16.h>

// B=256, S=512, D=128, R=2048, H=0.5
#define Bn 256
#define Sn 512
#define Dn 128
#define Rn 2048
#define TBv 64            // time-block
#define NBLK (Sn / TBv)   // 8 time-blocks
#define RG 256            // r-slice per workgroup (G=8)
#define LDX 132           // Xs row stride (bf16): 264B -> +2 banks/row
#define LDPs 260          // PX row stride (bf16): 520B -> +2 banks/row

using bf16_t = __hip_bfloat16;
typedef short bf16x8 __attribute__((ext_vector_type(8)));
typedef float f32x4 __attribute__((ext_vector_type(4)));
typedef float f32x2 __attribute__((ext_vector_type(2)));

__device__ __forceinline__ f32x2 clip2(f32x2 v) {
  v = __builtin_elementwise_max(v, (f32x2)(-5.f));
  v = __builtin_elementwise_min(v, (f32x2)(5.f));
  return v;
}
// fp32 -> bf16 bits, round-to-nearest-even (values finite/clamped here).
__device__ __forceinline__ unsigned bf16rne(float f) {
  const unsigned u = __float_as_uint(f);
  return (u + 0x7fffu + ((u >> 16) & 1u)) >> 16;
}
__device__ __forceinline__ unsigned pack_bf16(f32x2 v) {
  return (bf16rne(v.y) << 16) | (bf16rne(v.x) & 0xffffu);
}

// K0: preds := bias broadcast; weights fp32->bf16; zero losses. Grid 16384x256.
__global__ __launch_bounds__(256) void k_init(const float* __restrict__ Wp,
                                              const float* __restrict__ Wr,
                                              const float* __restrict__ br,
                                              bf16_t* __restrict__ Wp_b,
                                              bf16_t* __restrict__ Wr_b,
                                              float* __restrict__ preds,
                                              float* __restrict__ losses) {
  const int i = blockIdx.x * 256 + threadIdx.x;  // f32x4 index over Bn*Sn*Dn/4
  const f32x4 bv = *(const f32x4*)(br + (i & 31) * 4);
  *((f32x4*)preds + i) = bv;
  if (i < Rn * Dn) {
    Wp_b[i] = __float2bfloat16(Wp[i]);
    Wr_b[i] = __float2bfloat16(Wr[i]);
  }
  if (i == 0) { losses[0] = 0.f; losses[1] = 0.f; }
}

// K1: input oscillator scan per (b,d) -> Xin bf16 [b][t][d]; pc_loss_in.
// 256 blocks x 128 threads; 16-step chunked input prefetch.
__global__ __launch_bounds__(128) void k_inosc(const float* __restrict__ inp,
                                               const float* __restrict__ om,
                                               const float* __restrict__ ga,
                                               const float* __restrict__ al,
                                               bf16_t* __restrict__ Xin,
                                               float* __restrict__ loss_in) {
  const int d = threadIdx.x, b = blockIdx.x;
  const float w2 = om[d] * om[d];
  const float g2 = 2.f * fabsf(ga[d]);
  const float a = al[d];
  const float* ip = inp + (size_t)b * Sn * Dn + d;
  bf16_t* xp = Xin + (size_t)b * Sn * Dn + d;
  float x = 0.f, y = 0.f, pc = 0.f;
  float fv[16];
#pragma unroll
  for (int j = 0; j < 16; ++j) fv[j] = __builtin_nontemporal_load(ip + (size_t)j * Dn);
  for (int tb = 0; tb < 32; ++tb) {
    float fn[16];
    if (tb < 31) {
#pragma unroll
      for (int j = 0; j < 16; ++j)
        fn[j] = __builtin_nontemporal_load(ip + (size_t)((tb + 1) * 16 + j) * Dn);
    }
#pragma unroll
    for (int j = 0; j < 16; ++j) {
      const int t = tb * 16 + j;
      const float f = fv[j];
      if (t > 0) { const float e = x - f; pc += e * e; }
      const float accel = a * f - g2 * y - w2 * x;
      const float xn = fminf(fmaxf(x + 0.5f * y, -5.f), 5.f);
      const float yn = fminf(fmaxf(y + 0.5f * accel, -5.f), 5.f);
      xp[(size_t)t * Dn] = __float2bfloat16(xn);
      x = xn; y = yn;
    }
#pragma unroll
    for (int j = 0; j < 16; ++j) fv[j] = fn[j];
  }
#pragma unroll
  for (int o = 32; o > 0; o >>= 1) pc += __shfl_down(pc, o, 64);
  if ((threadIdx.x & 63) == 0)
    atomicAdd(loss_in, pc * (1.f / ((float)Bn * (float)Dn)));
}

// K2: fused proj GEMM + reservoir/output scan + readout GEMM.
// Grid Bn*8: b = idx>>3, r-slice g = idx&7. 512 thr (8 waves), ~50KB LDS -> 3 WGs/CU.
__global__ __launch_bounds__(512, 6) void k_fused(
    const bf16_t* __restrict__ Xin,
    const bf16_t* __restrict__ Wp, const float* __restrict__ bp,
    const float* __restrict__ omr, const float* __restrict__ gar,
    const float* __restrict__ alr,
    const float* __restrict__ omo, const float* __restrict__ gao,
    const float* __restrict__ alo,
    const bf16_t* __restrict__ Wr,
    float* __restrict__ preds, float* __restrict__ loss_out) {
  __shared__ bf16_t Xs[TBv * LDX];    // 16.5 KB
  __shared__ bf16_t PX[TBv * LDPs];   // 32.5 KB (proj slice, x_out in place)
  __shared__ float bpS[RG];           // 1 KB
  __shared__ float smo[8];

  const int tid = threadIdx.x;
  const int b = blockIdx.x >> 3, g = blockIdx.x & 7;
  const int rbase = g * RG;
  const int wv = tid >> 6, lane = tid & 63;
  const int lr = lane & 15, lq = lane >> 4;

  if (tid < RG) bpS[tid] = bp[rbase + tid];

  // reservoir/output oscillator state: threads 0..127 own local r = tid*2, tid*2+1
  f32x2 xr = (f32x2)0.f, yr = (f32x2)0.f, xo = (f32x2)0.f, yo = (f32x2)0.f;
  f32x2 w2r = (f32x2)0.f, g2r = (f32x2)0.f, arv = (f32x2)0.f;
  f32x2 w2o = (f32x2)0.f, g2o = (f32x2)0.f, aov = (f32x2)0.f;
  if (tid < 128) {
    const int rg = rbase + tid * 2;
    f32x2 t;
    t = *(const f32x2*)(omr + rg); w2r = t * t;
    t = *(const f32x2*)(gar + rg); g2r = __builtin_elementwise_abs(t) * 2.f;
    arv = *(const f32x2*)(alr + rg);
    t = *(const f32x2*)(omo + rg); w2o = t * t;
    t = *(const f32x2*)(gao + rg); g2o = __builtin_elementwise_abs(t) * 2.f;
    aov = *(const f32x2*)(alo + rg);
  }
  f32x2 pc_out2 = (f32x2)0.f;

  const bf16_t* xinb = Xin + (size_t)b * Sn * Dn;

  // prologue: stage first Xin tile (64 x 128 bf16; 1024 16B chunks, 2/thread)
  {
    const int c0 = tid, c1 = tid + 512;
    *(uint4*)&Xs[(c0 >> 4) * LDX + (c0 & 15) * 8] =
        *(const uint4*)(xinb + (size_t)(c0 >> 4) * Dn + (c0 & 15) * 8);
    *(uint4*)&Xs[(c1 >> 4) * LDX + (c1 & 15) * 8] =
        *(const uint4*)(xinb + (size_t)(c1 >> 4) * Dn + (c1 & 15) * 8);
  }
  __syncthreads();

  for (int blk = 0; blk < NBLK; ++blk) {
    const int t0 = blk * TBv;

    // ---- Phase B: proj slice [64 x 256] = Xs[64x128] @ Wp_slice^T -> PX ----
    {
      const int cb = wv * 32;  // wave's 32 local cols (2 tiles of 16)
#pragma unroll
      for (int ct = 0; ct < 2; ++ct) {
        const int cl = cb + ct * 16;
        const bf16_t* wpb = Wp + (size_t)(rbase + cl + lr) * Dn + lq * 8;
        bf16x8 bf[4];
#pragma unroll
        for (int k = 0; k < 4; ++k) bf[k] = *(const bf16x8*)(wpb + k * 32);
        f32x4 acc[4];
#pragma unroll
        for (int rt = 0; rt < 4; ++rt) {
          bf16x8 af[4];
#pragma unroll
          for (int k = 0; k < 4; ++k)
            af[k] = *(const bf16x8*)&Xs[(rt * 16 + lr) * LDX + k * 32 + lq * 8];
          f32x4 a = (f32x4)0.f;
#pragma unroll
          for (int k = 0; k < 4; ++k)
            a = __builtin_amdgcn_mfma_f32_16x16x32_bf16(af[k], bf[k], a, 0, 0, 0);
          acc[rt] = a;
        }
        const float bv = bpS[cl + lr];
#pragma unroll
        for (int rt = 0; rt < 4; ++rt)
#pragma unroll
          for (int r = 0; r < 4; ++r)
            PX[(rt * 16 + lq * 4 + r) * LDPs + cl + lr] = __float2bfloat16(acc[rt][r] + bv);
      }
    }
    __syncthreads();

    // ---- Phase C: reservoir + output oscillators, in place (threads 0..127) ----
    if (tid < 128) {
      const int rl = tid * 2;
      unsigned pk = *(unsigned*)&PX[0 * LDPs + rl];
      for (int tt = 0; tt < TBv; ++tt) {
        unsigned pk_n = pk;
        if (tt + 1 < TBv) pk_n = *(unsigned*)&PX[(tt + 1) * LDPs + rl];
        f32x2 pv;
        pv.x = __uint_as_float(pk << 16);
        pv.y = __uint_as_float(pk & 0xffff0000u);
        f32x2 acr = arv * pv - g2r * yr - w2r * xr;
        f32x2 xrn = clip2(xr + yr * 0.5f);
        f32x2 yrn = clip2(yr + acr * 0.5f);
        f32x2 aco = aov * xrn - g2o * yo - w2o * xo;
        f32x2 xon = clip2(xo + yo * 0.5f);
        f32x2 yon = clip2(yo + aco * 0.5f);
        f32x2 e = xon - xrn;
        pc_out2 += e * e;
        xr = xrn; yr = yrn; xo = xon; yo = yon;
        *(unsigned*)&PX[tt * LDPs + rl] = pack_bf16(xon);
        pk = pk_n;
      }
    }
    __syncthreads();

    // ---- stage next Xin tile into regs (latency hidden under D) ----
    uint4 sv0, sv1;
    if (blk + 1 < NBLK) {
      const bf16_t* src = xinb + (size_t)(t0 + TBv) * Dn;
      const int c0 = tid, c1 = tid + 512;
      sv0 = *(const uint4*)(src + (size_t)(c0 >> 4) * Dn + (c0 & 15) * 8);
      sv1 = *(const uint4*)(src + (size_t)(c1 >> 4) * Dn + (c1 & 15) * 8);
    }

    // ---- Phase D: preds[64 x 128] += PX[64x256] @ Wr[:, slice]^T (atomic) ----
    {
      const int d0 = wv * 16;
      const bf16_t* wrb = Wr + (size_t)(d0 + lr) * Rn + rbase + lq * 8;
      f32x4 acc[4] = {(f32x4)0.f, (f32x4)0.f, (f32x4)0.f, (f32x4)0.f};
      bf16x8 bcur = *(const bf16x8*)(wrb);
#pragma unroll
      for (int k0 = 0; k0 < RG; k0 += 32) {
        bf16x8 bnxt = bcur;
        if (k0 + 32 < RG) bnxt = *(const bf16x8*)(wrb + k0 + 32);
#pragma unroll
        for (int rt = 0; rt < 4; ++rt) {
          bf16x8 a = *(const bf16x8*)&PX[(rt * 16 + lr) * LDPs + k0 + lq * 8];
          acc[rt] = __builtin_amdgcn_mfma_f32_16x16x32_bf16(a, bcur, acc[rt], 0, 0, 0);
        }
        bcur = bnxt;
      }
      float* outb = preds + (size_t)b * Sn * Dn + (size_t)t0 * Dn;
      const int col = d0 + lr;
#pragma unroll
      for (int rt = 0; rt < 4; ++rt)
#pragma unroll
        for (int r = 0; r < 4; ++r)
          atomicAdd(outb + (size_t)(rt * 16 + lq * 4 + r) * Dn + col, acc[rt][r]);
    }

    // write staged tile to Xs (Xs reads finished at the B->C barrier)
    if (blk + 1 < NBLK) {
      const int c0 = tid, c1 = tid + 512;
      *(uint4*)&Xs[(c0 >> 4) * LDX + (c0 & 15) * 8] = sv0;
      *(uint4*)&Xs[(c1 >> 4) * LDX + (c1 & 15) * 8] = sv1;
    }
    __syncthreads();  // Xs staged AND PX reads drained -> next B may write PX
  }

  // ---- pc_loss_out reduction: one atomicAdd per WG ----
  float vo = pc_out2.x + pc_out2.y;
#pragma unroll
  for (int o = 32; o > 0; o >>= 1) vo += __shfl_down(vo, o, 64);
  if (lane == 0) smo[wv] = vo;
  __syncthreads();
  if (tid == 0) {
    float so = 0.f;
#pragma unroll
    for (int w = 0; w < 8; ++w) so += smo[w];
    atomicAdd(loss_out, so * (1.f / ((float)Bn * (float)Rn)));
  }
}

extern "C" void kernel_launch(void* const* d_in, const int* in_sizes, int n_in,
                              void* d_out, int out_size, void* d_ws, size_t ws_size,
                              hipStream_t stream) {
  const float* inputs    = (const float*)d_in[0];
  const float* omega_in  = (const float*)d_in[1];
  const float* gamma_in  = (const float*)d_in[2];
  const float* alpha_in  = (const float*)d_in[3];
  const float* W_proj    = (const float*)d_in[4];
  const float* b_proj    = (const float*)d_in[5];
  const float* omega_res = (const float*)d_in[6];
  const float* gamma_res = (const float*)d_in[7];
  const float* alpha_res = (const float*)d_in[8];
  const float* omega_out = (const float*)d_in[9];
  const float* gamma_out = (const float*)d_in[10];
  const float* alpha_out = (const float*)d_in[11];
  const float* W_read    = (const float*)d_in[12];
  const float* b_read    = (const float*)d_in[13];

  float* out = (float*)d_out;
  float* losses = out + (size_t)Bn * Sn * Dn;  // preds | pc_loss_in | pc_loss_out

  // ws: Wp_b 512KB | Wr_b 512KB | Xin bf16 32MB  (~33MB total)
  bf16_t* Wp_b = (bf16_t*)d_ws;
  bf16_t* Wr_b = Wp_b + (size_t)Rn * Dn;
  bf16_t* Xin  = Wr_b + (size_t)Rn * Dn;

  k_init<<<(Bn * Sn * Dn / 4) / 256, 256, 0, stream>>>(W_proj, W_read, b_read,
                                                       Wp_b, Wr_b, out, losses);
  k_inosc<<<Bn, 128, 0, stream>>>(inputs, omega_in, gamma_in, alpha_in, Xin, losses);
  k_fused<<<Bn * 8, 512, 0, stream>>>(Xin, Wp_b, b_proj,
                                      omega_res, gamma_res, alpha_res,
                                      omega_out, gamma_out, alpha_out,
                                      Wr_b, out, losses + 1);
}